// Round 3
// baseline (60.451 us; speedup 1.0000x reference)
//
#include <hip/hip_runtime.h>

// NODE ensemble forward, round 2 — 3-kernel split for attribution + speed.
//   K1 pack: fsel fp32 -> bf16 MFMA B-frag layout (pk); lw -> lwT[leaf][tree]
//   K2 gemm: probs = sigmoid(x @ fsel^T - thr), bf16, written to ws
//            256 blocks x 512 thr, 64 rows/block, K=2x256 reg-staged dbuf
//   K3 fold: out[b] = sum_t fold(probs[b,t,:], lwT[:,t]); lane=tree
//
// B=16384, D=512, T=64, DEPTH=6, NCOL=384.

#define DD     512
#define NCOL   384
#define NDEPTH 6
#define BM     64          // rows per gemm block
#define CHK    256         // K chunk
#define XSTR   264         // bf16 LDS row stride (256 + 8 pad -> 2-way free)

typedef __bf16 bf16_t;
typedef __bf16 bf16x8 __attribute__((ext_vector_type(8)));
typedef __bf16 bf16x4 __attribute__((ext_vector_type(4)));
typedef float  f32x4  __attribute__((ext_vector_type(4)));

static __device__ __forceinline__ float b2f(unsigned int u16) {
  unsigned int t = u16 << 16;
  float f;
  __builtin_memcpy(&f, &t, 4);
  return f;
}

// pk[((cf*16 + ksg)*64 + lane)*8 + j] = fsel[cf*16+(lane&15)][ksg*32+(lane>>4)*8+j]
// block 96: lwT[j*64 + t] = lw[t*64 + j]
__global__ __launch_bounds__(256) void node_pack(const float* __restrict__ fsel,
                                                 const float* __restrict__ lw,
                                                 bf16_t* __restrict__ pk,
                                                 float* __restrict__ lwT)
{
  if (blockIdx.x < 96) {
    int tid  = blockIdx.x * 256 + threadIdx.x;   // 0..24575
    int lane = tid & 63;
    int ksg  = (tid >> 6) & 15;
    int cf   = tid >> 10;                        // 0..23
    int col  = cf * 16 + (lane & 15);
    int k    = ksg * 32 + (lane >> 4) * 8;
    float4 f0 = *reinterpret_cast<const float4*>(fsel + (size_t)col * DD + k);
    float4 f1 = *reinterpret_cast<const float4*>(fsel + (size_t)col * DD + k + 4);
    bf16x8 v;
    v[0] = (bf16_t)f0.x; v[1] = (bf16_t)f0.y; v[2] = (bf16_t)f0.z; v[3] = (bf16_t)f0.w;
    v[4] = (bf16_t)f1.x; v[5] = (bf16_t)f1.y; v[6] = (bf16_t)f1.z; v[7] = (bf16_t)f1.w;
    *reinterpret_cast<bf16x8*>(pk + (size_t)tid * 8) = v;
  } else {
    #pragma unroll
    for (int it = 0; it < 16; ++it) {
      int i = it * 256 + threadIdx.x;            // 0..4095
      int t = i & 63, j = i >> 6;
      lwT[j * 64 + t] = lw[t * 64 + j];
    }
  }
}

__global__ __launch_bounds__(512) void node_gemm(
    const float*  __restrict__ x,      // [B][512]
    const bf16_t* __restrict__ pk,     // packed B frags
    const float*  __restrict__ thr,    // [384]
    bf16_t*       __restrict__ probs)  // [B][384]
{
  extern __shared__ char smem[];
  bf16_t* xs = (bf16_t*)smem;          // [2][BM][XSTR] = 67584 B

  const int tid  = threadIdx.x;
  const int lane = tid & 63;
  const int wv   = tid >> 6;
  const int rg   = wv >> 1;            // row group (0..3): rows rg*16..+15
  const int cg   = wv & 1;             // col group (0..1): cols cg*192..+191
  const int c    = lane & 15;
  const int kg   = lane >> 4;
  const int rowbase = blockIdx.x * BM;

  // ---- stage chunk 0 into regs ----
  float4 st[8];
  #pragma unroll
  for (int i = 0; i < 8; ++i) {
    int idx = i * 512 + tid;
    int e = idx << 2;
    int r = e >> 8, k = e & 255;
    st[i] = *reinterpret_cast<const float4*>(x + (size_t)(rowbase + r) * DD + k);
  }
  // cvt + write buf0
  #pragma unroll
  for (int i = 0; i < 8; ++i) {
    int idx = i * 512 + tid;
    int e = idx << 2;
    int r = e >> 8, k = e & 255;
    bf16x4 v;
    v[0] = (bf16_t)st[i].x; v[1] = (bf16_t)st[i].y;
    v[2] = (bf16_t)st[i].z; v[3] = (bf16_t)st[i].w;
    *reinterpret_cast<bf16x4*>(xs + r * XSTR + k) = v;
  }
  // issue chunk 1 loads (stay in flight across the barrier)
  #pragma unroll
  for (int i = 0; i < 8; ++i) {
    int idx = i * 512 + tid;
    int e = idx << 2;
    int r = e >> 8, k = e & 255;
    st[i] = *reinterpret_cast<const float4*>(x + (size_t)(rowbase + r) * DD + CHK + k);
  }
  asm volatile("s_waitcnt lgkmcnt(0)" ::: "memory");   // ds_writes visible, vmcnt NOT drained
  __builtin_amdgcn_s_barrier();

  f32x4 acc[12];
  #pragma unroll
  for (int f = 0; f < 12; ++f) acc[f] = (f32x4){0.f, 0.f, 0.f, 0.f};

  // per-wave B base: cf = cg*12 + f; frag(cf,ksg) at ((cf*16+ksg)*64+lane)*8
  const bf16_t* pkw = pk + (size_t)cg * 12 * 16 * 512 + (size_t)lane * 8;

  // ---- GEMM chunk 0 ----
  {
    const bf16_t* xa = xs + (rg * 16 + c) * XSTR + kg * 8;
    #pragma unroll 2
    for (int ks = 0; ks < 8; ++ks) {
      bf16x8 a = *reinterpret_cast<const bf16x8*>(xa + ks * 32);
      #pragma unroll
      for (int f = 0; f < 12; ++f) {
        bf16x8 b = *reinterpret_cast<const bf16x8*>(pkw + (size_t)(f * 16 + ks) * 512);
        acc[f] = __builtin_amdgcn_mfma_f32_16x16x32_bf16(a, b, acc[f], 0, 0, 0);
      }
    }
  }

  // cvt + write buf1 (vmcnt waits inserted by compiler via reg deps)
  #pragma unroll
  for (int i = 0; i < 8; ++i) {
    int idx = i * 512 + tid;
    int e = idx << 2;
    int r = e >> 8, k = e & 255;
    bf16x4 v;
    v[0] = (bf16_t)st[i].x; v[1] = (bf16_t)st[i].y;
    v[2] = (bf16_t)st[i].z; v[3] = (bf16_t)st[i].w;
    *reinterpret_cast<bf16x4*>(xs + BM * XSTR + r * XSTR + k) = v;
  }
  asm volatile("s_waitcnt lgkmcnt(0)" ::: "memory");
  __builtin_amdgcn_s_barrier();

  // ---- GEMM chunk 1 ----
  {
    const bf16_t* xa = xs + BM * XSTR + (rg * 16 + c) * XSTR + kg * 8;
    #pragma unroll 2
    for (int ks = 0; ks < 8; ++ks) {
      bf16x8 a = *reinterpret_cast<const bf16x8*>(xa + ks * 32);
      #pragma unroll
      for (int f = 0; f < 12; ++f) {
        bf16x8 b = *reinterpret_cast<const bf16x8*>(pkw + (size_t)(f * 16 + 8 + ks) * 512);
        acc[f] = __builtin_amdgcn_mfma_f32_16x16x32_bf16(a, b, acc[f], 0, 0, 0);
      }
    }
  }

  // ---- epilogue: sigmoid + store probs bf16 ----
  // D layout: row = rg*16 + kg*4 + reg, col = cg*192 + f*16 + c
  #pragma unroll
  for (int f = 0; f < 12; ++f) {
    const int col = cg * 192 + f * 16 + c;
    const float th = thr[col];
    #pragma unroll
    for (int reg = 0; reg < 4; ++reg) {
      float z = acc[f][reg] - th;
      float p = 1.0f / (1.0f + __expf(-z));
      probs[(size_t)(rowbase + rg * 16 + kg * 4 + reg) * NCOL + col] = (bf16_t)p;
    }
  }
}

__global__ __launch_bounds__(256) void node_fold(
    const bf16_t* __restrict__ probs,  // [B][384]
    const float*  __restrict__ lwT,    // [64 leaves][64 trees]
    float*        __restrict__ out)    // [B]
{
  const int lane = threadIdx.x & 63;
  const int wv   = threadIdx.x >> 6;
  const int rowbase = blockIdx.x * 16 + wv * 4;

  float w[64];
  #pragma unroll
  for (int j = 0; j < 64; ++j) w[j] = lwT[j * 64 + lane];   // coalesced

  #pragma unroll
  for (int rr = 0; rr < 4; ++rr) {
    const unsigned int* pr =
        reinterpret_cast<const unsigned int*>(probs + (size_t)(rowbase + rr) * NCOL) + lane * 3;
    unsigned int d0 = pr[0], d1 = pr[1], d2 = pr[2];
    float p[NDEPTH];
    p[0] = b2f(d0 & 0xffffu); p[1] = b2f(d0 >> 16);
    p[2] = b2f(d1 & 0xffffu); p[3] = b2f(d1 >> 16);
    p[4] = b2f(d2 & 0xffffu); p[5] = b2f(d2 >> 16);

    float v[32];
    #pragma unroll
    for (int j = 0; j < 32; ++j) v[j] = fmaf(p[5], w[2*j] - w[2*j+1], w[2*j+1]);
    #pragma unroll
    for (int j = 0; j < 16; ++j) v[j] = fmaf(p[4], v[2*j] - v[2*j+1], v[2*j+1]);
    #pragma unroll
    for (int j = 0; j < 8;  ++j) v[j] = fmaf(p[3], v[2*j] - v[2*j+1], v[2*j+1]);
    #pragma unroll
    for (int j = 0; j < 4;  ++j) v[j] = fmaf(p[2], v[2*j] - v[2*j+1], v[2*j+1]);
    #pragma unroll
    for (int j = 0; j < 2;  ++j) v[j] = fmaf(p[1], v[2*j] - v[2*j+1], v[2*j+1]);
    float tv = fmaf(p[0], v[0] - v[1], v[1]);

    #pragma unroll
    for (int off = 32; off; off >>= 1) tv += __shfl_xor(tv, off, 64);
    if (lane == 0) out[rowbase + rr] = tv;
  }
}

extern "C" void kernel_launch(void* const* d_in, const int* in_sizes, int n_in,
                              void* d_out, int out_size, void* d_ws, size_t ws_size,
                              hipStream_t stream) {
  const float* x    = (const float*)d_in[0];
  const float* fsel = (const float*)d_in[1];
  const float* thr  = (const float*)d_in[2];
  const float* lw   = (const float*)d_in[3];
  float* out = (float*)d_out;

  char* ws = (char*)d_ws;
  bf16_t* pk    = (bf16_t*)ws;                    // 393216 B
  float*  lwT   = (float*)(ws + 393216);          // 16384 B
  bf16_t* probs = (bf16_t*)(ws + 409600);         // 12.6 MB

  const int B = in_sizes[0] / DD;                 // 16384
  const int lds = 2 * BM * XSTR * 2;              // 67584 B

  node_pack<<<dim3(97), dim3(256), 0, stream>>>(fsel, lw, pk, lwT);
  node_gemm<<<dim3(B / BM), dim3(512), lds, stream>>>(x, pk, thr, probs);
  node_fold<<<dim3(B / 16), dim3(256), 0, stream>>>(probs, lwT, out);
}

// Round 4
// 31.113 us; speedup vs baseline: 1.9430x; 1.9430x over previous
//
#include <hip/hip_runtime.h>

// NODE ensemble forward, round 3 — B-in-registers GEMM.
//   K1 pack: fsel fp32 -> bf16 MFMA B-frag layout (pk); lw -> lwT[leaf][tree]
//   K2 gemm: 256 blocks x 512 thr (8 waves, 1 block/CU). Each wave holds its
//            48 cols x K=512 of B in 192 VGPRs (loaded once). x streamed via
//            LDS in frag layout, 16-row tiles, double-buffered, raw s_barrier
//            + lgkmcnt-only (loads stay in flight). probs = sigmoid bf16 -> ws.
//   K3 fold: out[b] = sum_t fold(probs[b,t,:], lwT[:,t]); lane=tree.
//
// B=16384, D=512, T=64, DEPTH=6, NCOL=384.

#define DD     512
#define NCOL   384
#define NDEPTH 6

typedef __bf16 bf16_t;
typedef __bf16 bf16x8 __attribute__((ext_vector_type(8)));
typedef float  f32x4  __attribute__((ext_vector_type(4)));

static __device__ __forceinline__ float b2f(unsigned int u16) {
  unsigned int t = u16 << 16;
  float f;
  __builtin_memcpy(&f, &t, 4);
  return f;
}

// pk[((cf*16 + ksg)*64 + lane)*8 + j] = fsel[cf*16+(lane&15)][ksg*32+(lane>>4)*8+j]
// block 96: lwT[j*64 + t] = lw[t*64 + j]
__global__ __launch_bounds__(256) void node_pack(const float* __restrict__ fsel,
                                                 const float* __restrict__ lw,
                                                 bf16_t* __restrict__ pk,
                                                 float* __restrict__ lwT)
{
  if (blockIdx.x < 96) {
    int tid  = blockIdx.x * 256 + threadIdx.x;   // 0..24575
    int lane = tid & 63;
    int ksg  = (tid >> 6) & 15;
    int cf   = tid >> 10;                        // 0..23
    int col  = cf * 16 + (lane & 15);
    int k    = ksg * 32 + (lane >> 4) * 8;
    float4 f0 = *reinterpret_cast<const float4*>(fsel + (size_t)col * DD + k);
    float4 f1 = *reinterpret_cast<const float4*>(fsel + (size_t)col * DD + k + 4);
    bf16x8 v;
    v[0] = (bf16_t)f0.x; v[1] = (bf16_t)f0.y; v[2] = (bf16_t)f0.z; v[3] = (bf16_t)f0.w;
    v[4] = (bf16_t)f1.x; v[5] = (bf16_t)f1.y; v[6] = (bf16_t)f1.z; v[7] = (bf16_t)f1.w;
    *reinterpret_cast<bf16x8*>(pk + (size_t)tid * 8) = v;
  } else {
    #pragma unroll
    for (int it = 0; it < 16; ++it) {
      int i = it * 256 + threadIdx.x;            // 0..4095
      int t = i & 63, j = i >> 6;
      lwT[j * 64 + t] = lw[t * 64 + j];
    }
  }
}

__global__ __launch_bounds__(512, 2) void node_gemm(
    const float*  __restrict__ x,      // [B][512]
    const bf16_t* __restrict__ pk,     // packed B frags
    const float*  __restrict__ thr,    // [384]
    bf16_t*       __restrict__ probs)  // [B][384]
{
  // x-tile in MFMA frag layout: xf[buf][(ks*64 + lane)*8 + j]
  //   = x[tile_row + (lane&15)][ks*32 + (lane>>4)*8 + j]  (bf16)
  __shared__ bf16_t xf[2][8192];       // 2 x 16 KiB

  const int tid  = threadIdx.x;
  const int lane = tid & 63;
  const int wv   = tid >> 6;           // 0..7; wave owns cols wv*48..+47
  const int rowblk = blockIdx.x * 64;
  const int srow = lane & 15;
  const int skg  = lane >> 4;

  // ---- B into registers: 3 col-frags x 16 k-steps, loaded once ----
  bf16x8 breg[3][16];
  #pragma unroll
  for (int f = 0; f < 3; ++f) {
    #pragma unroll
    for (int ks = 0; ks < 16; ++ks) {
      breg[f][ks] = *reinterpret_cast<const bf16x8*>(
          pk + ((size_t)(((wv * 3 + f) * 16 + ks) * 64) + lane) * 8);
    }
  }

  float th[3];
  #pragma unroll
  for (int f = 0; f < 3; ++f) th[f] = thr[wv * 48 + f * 16 + (lane & 15)];

  // staging: wave wv covers ks = wv and wv+8 for the 16-row tile
  float4 st[4];

  #define ISSUE_LOADS(t)                                                        \
    do {                                                                        \
      const float* base_ = x + (size_t)(rowblk + (t) * 16 + srow) * DD + skg*8; \
      st[0] = *reinterpret_cast<const float4*>(base_ + wv * 32);                \
      st[1] = *reinterpret_cast<const float4*>(base_ + wv * 32 + 4);            \
      st[2] = *reinterpret_cast<const float4*>(base_ + (wv + 8) * 32);          \
      st[3] = *reinterpret_cast<const float4*>(base_ + (wv + 8) * 32 + 4);      \
    } while (0)

  #define WRITE_LDS(buf)                                                        \
    do {                                                                        \
      bf16x8 v0_, v1_;                                                          \
      v0_[0]=(bf16_t)st[0].x; v0_[1]=(bf16_t)st[0].y;                           \
      v0_[2]=(bf16_t)st[0].z; v0_[3]=(bf16_t)st[0].w;                           \
      v0_[4]=(bf16_t)st[1].x; v0_[5]=(bf16_t)st[1].y;                           \
      v0_[6]=(bf16_t)st[1].z; v0_[7]=(bf16_t)st[1].w;                           \
      v1_[0]=(bf16_t)st[2].x; v1_[1]=(bf16_t)st[2].y;                           \
      v1_[2]=(bf16_t)st[2].z; v1_[3]=(bf16_t)st[2].w;                           \
      v1_[4]=(bf16_t)st[3].x; v1_[5]=(bf16_t)st[3].y;                           \
      v1_[6]=(bf16_t)st[3].z; v1_[7]=(bf16_t)st[3].w;                           \
      *reinterpret_cast<bf16x8*>(&xf[buf][(wv * 64 + lane) * 8])       = v0_;   \
      *reinterpret_cast<bf16x8*>(&xf[buf][((wv + 8) * 64 + lane) * 8]) = v1_;   \
    } while (0)

  // ---- preamble: stage tile 0, issue tile-1 loads ----
  ISSUE_LOADS(0);
  WRITE_LDS(0);
  ISSUE_LOADS(1);
  asm volatile("s_waitcnt lgkmcnt(0)" ::: "memory");
  __builtin_amdgcn_s_barrier();

  // ---- 4 tiles of 16 rows ----
  #pragma unroll
  for (int t = 0; t < 4; ++t) {
    const int buf = t & 1;
    if (t < 3) WRITE_LDS(buf ^ 1);   // tile t+1 data (vmcnt wait via reg deps)
    if (t < 2) ISSUE_LOADS(t + 2);

    f32x4 acc[3];
    #pragma unroll
    for (int f = 0; f < 3; ++f) acc[f] = (f32x4){0.f, 0.f, 0.f, 0.f};

    #pragma unroll
    for (int ks = 0; ks < 16; ++ks) {
      bf16x8 a = *reinterpret_cast<const bf16x8*>(&xf[buf][(ks * 64 + lane) * 8]);
      acc[0] = __builtin_amdgcn_mfma_f32_16x16x32_bf16(a, breg[0][ks], acc[0], 0, 0, 0);
      acc[1] = __builtin_amdgcn_mfma_f32_16x16x32_bf16(a, breg[1][ks], acc[1], 0, 0, 0);
      acc[2] = __builtin_amdgcn_mfma_f32_16x16x32_bf16(a, breg[2][ks], acc[2], 0, 0, 0);
    }

    // epilogue: sigmoid + bf16 store. D: row=(lane>>4)*4+r, col=f*16+(lane&15)
    #pragma unroll
    for (int f = 0; f < 3; ++f) {
      const int col = wv * 48 + f * 16 + (lane & 15);
      #pragma unroll
      for (int r = 0; r < 4; ++r) {
        const int row = rowblk + t * 16 + (lane >> 4) * 4 + r;
        float z = acc[f][r] - th[f];
        float p = 1.0f / (1.0f + __expf(-z));
        probs[(size_t)row * NCOL + col] = (bf16_t)p;
      }
    }

    if (t < 3) {
      asm volatile("s_waitcnt lgkmcnt(0)" ::: "memory");
      __builtin_amdgcn_s_barrier();
    }
  }
  #undef ISSUE_LOADS
  #undef WRITE_LDS
}

__global__ __launch_bounds__(256) void node_fold(
    const bf16_t* __restrict__ probs,  // [B][384]
    const float*  __restrict__ lwT,    // [64 leaves][64 trees]
    float*        __restrict__ out)    // [B]
{
  const int lane = threadIdx.x & 63;
  const int wv   = threadIdx.x >> 6;
  const int rowbase = blockIdx.x * 16 + wv * 4;

  float w[64];
  #pragma unroll
  for (int j = 0; j < 64; ++j) w[j] = lwT[j * 64 + lane];   // coalesced

  #pragma unroll
  for (int rr = 0; rr < 4; ++rr) {
    const unsigned int* pr =
        reinterpret_cast<const unsigned int*>(probs + (size_t)(rowbase + rr) * NCOL) + lane * 3;
    unsigned int d0 = pr[0], d1 = pr[1], d2 = pr[2];
    float p[NDEPTH];
    p[0] = b2f(d0 & 0xffffu); p[1] = b2f(d0 >> 16);
    p[2] = b2f(d1 & 0xffffu); p[3] = b2f(d1 >> 16);
    p[4] = b2f(d2 & 0xffffu); p[5] = b2f(d2 >> 16);

    float v[32];
    #pragma unroll
    for (int j = 0; j < 32; ++j) v[j] = fmaf(p[5], w[2*j] - w[2*j+1], w[2*j+1]);
    #pragma unroll
    for (int j = 0; j < 16; ++j) v[j] = fmaf(p[4], v[2*j] - v[2*j+1], v[2*j+1]);
    #pragma unroll
    for (int j = 0; j < 8;  ++j) v[j] = fmaf(p[3], v[2*j] - v[2*j+1], v[2*j+1]);
    #pragma unroll
    for (int j = 0; j < 4;  ++j) v[j] = fmaf(p[2], v[2*j] - v[2*j+1], v[2*j+1]);
    #pragma unroll
    for (int j = 0; j < 2;  ++j) v[j] = fmaf(p[1], v[2*j] - v[2*j+1], v[2*j+1]);
    float tv = fmaf(p[0], v[0] - v[1], v[1]);

    #pragma unroll
    for (int off = 32; off; off >>= 1) tv += __shfl_xor(tv, off, 64);
    if (lane == 0) out[rowbase + rr] = tv;
  }
}

extern "C" void kernel_launch(void* const* d_in, const int* in_sizes, int n_in,
                              void* d_out, int out_size, void* d_ws, size_t ws_size,
                              hipStream_t stream) {
  const float* x    = (const float*)d_in[0];
  const float* fsel = (const float*)d_in[1];
  const float* thr  = (const float*)d_in[2];
  const float* lw   = (const float*)d_in[3];
  float* out = (float*)d_out;

  char* ws = (char*)d_ws;
  bf16_t* pk    = (bf16_t*)ws;                    // 393216 B
  float*  lwT   = (float*)(ws + 393216);          // 16384 B
  bf16_t* probs = (bf16_t*)(ws + 409600);         // 12.6 MB

  const int B = in_sizes[0] / DD;                 // 16384

  node_pack<<<dim3(97), dim3(256), 0, stream>>>(fsel, lw, pk, lwT);
  node_gemm<<<dim3(B / 64), dim3(512), 0, stream>>>(x, pk, thr, probs);
  node_fold<<<dim3(B / 16), dim3(256), 0, stream>>>(probs, lwT, out);
}